// Round 17
// baseline (24.837 us; speedup 1.0000x reference)
//
#include <hip/hip_runtime.h>

typedef float f32x4 __attribute__((ext_vector_type(4)));
typedef float f32x16 __attribute__((ext_vector_type(16)));
typedef _Float16 f16x8 __attribute__((ext_vector_type(8)));
typedef __fp16 fp16x2 __attribute__((ext_vector_type(2)));
typedef int i32x2 __attribute__((ext_vector_type(2)));

static __device__ __forceinline__ unsigned pk2(float a, float b) {
    fp16x2 r = __builtin_amdgcn_cvt_pkrtz(a, b); // v_cvt_pkrtz_f16_f32
    return __builtin_bit_cast(unsigned, r);
}
static __device__ __forceinline__ f16x8 pk8(float4 a, float4 b) {
    uint4 u; u.x = pk2(a.x, a.y); u.y = pk2(a.z, a.w);
    u.z = pk2(b.x, b.y); u.w = pk2(b.z, b.w);
    return __builtin_bit_cast(f16x8, u);
}

#define MFMA32(A, B, C) __builtin_amdgcn_mfma_f32_32x32x16_f16((A), (B), (C), 0, 0, 0)

// qkv: [2][2048][3][16][64] f32; layout: [128][8] i32; out: [2][2048][16][64] f32
// r15 shell (24.26us): wg = 4 waves x 32 q = 128 q-rows (b,h,j,qh), 512 wgs -> 2 wg/CU;
// 64-key K/V tiles dbuf'd in swizzled LDS, 1 barrier/tile; cross-chunk interleaved body;
// in-reg P (cvt_pkrtz + permlane32_swap); fixed-base softmax (Q pre-scaled by
// 0.125*log2e); raw v_exp_f32. NEW: MFMA chain-depth split -- QK uses two partial
// accumulators per chunk (4 indep streams, chains 4->2) and PV uses one accumulator
// per (dt,ksi) (accs[2][2], summed in epilogue; removes cross-chunk acc serialization).
__global__ __launch_bounds__(256, 2) void fba_fwd(const float* __restrict__ qkv,
                                                  const int* __restrict__ layout,
                                                  float* __restrict__ out) {
    __shared__ unsigned short Klds[2][64 * 64];  // [key][d] f16, byte ^= (key&7)<<4
    __shared__ unsigned short Vtlds[2][64 * 64]; // [d][key] f16, byte ^= ((d^(d>>3))&7)<<4

    const int bid = blockIdx.x;
    const int vid = (bid & 7) * 64 + (bid >> 3); // XCD swizzle: one (b,h) per XCD
    const int b = vid >> 8;
    const int hh = (vid >> 4) & 15;
    const int j = (vid >> 1) & 7;
    const int qh = vid & 1;

    const int tid = threadIdx.x;
    const int w = tid >> 6;
    const int lane = tid & 63;
    const int l31 = lane & 31;
    const int h = lane >> 5;

    const size_t bbase = (size_t)b * 2048 * 3072;
    const int qbase = 256 * j + 128 * qh + 32 * w;

    // active K-blocks for this wg's 8 layout rows (uniform): pack ids into nibbles
    unsigned kbl = 0; int nact = 0;
    for (int kb = 0; kb < 8; ++kb) {
        int a = 0;
        #pragma unroll
        for (int r = 0; r < 8; ++r) a |= layout[(16 * j + 8 * qh + r) * 8 + kb];
        if (a) { kbl |= (unsigned)kb << (4 * nact); ++nact; }
    }
    kbl = __builtin_amdgcn_readfirstlane(kbl);
    const int ntile = 4 * nact; // 64-key tiles

    // Q frags (B-operand, pre-scaled): lane -> Q[q=qbase+l31][d = ds*16+8h+e] * SC
    const float SC = 0.18033688f; // 0.125 * log2(e)
    f16x8 qf[4];
    {
        const float* qp = qkv + bbase + (size_t)(qbase + l31) * 3072 + hh * 64;
        #pragma unroll
        for (int ds = 0; ds < 4; ++ds) {
            const float* p0 = qp + ds * 16 + 8 * h;
            float4 x = *(const float4*)p0;
            float4 y = *(const float4*)(p0 + 4);
            float4 xs = {x.x * SC, x.y * SC, x.z * SC, x.w * SC};
            float4 ys = {y.x * SC, y.y * SC, y.z * SC, y.w * SC};
            qf[ds] = pk8(xs, ys);
        }
    }

    // accs[dt][ksi]: O^T partial over ksi-subset of keys; summed in epilogue.
    f32x16 accs[2][2];
    accs[0][0] = (f32x16)(0.f); accs[0][1] = (f32x16)(0.f);
    accs[1][0] = (f32x16)(0.f); accs[1][1] = (f32x16)(0.f);
    float lsum = 0.f;

    // staging thread-constants (256 threads): K keys skey+16m (m<4); V pairs 2skey+32p
    const int skey = tid >> 4;  // 0..15
    const int sdc  = tid & 15;  // d-group of 4 floats

    float4 kr0, kr1, kr2, kr3;  // K prefetch (4 float4)
    float4 va0, vb0, va1, vb1;  // V prefetch (4 float4) -- 8 total: proven no-spill

#define STAGE_LOAD(ks_) {                                                           \
    const float* kp_ = qkv + bbase + (size_t)((ks_) + skey) * 3072 + 1024 + hh * 64 + sdc * 4; \
    kr0 = *(const float4*)kp_;                                                      \
    kr1 = *(const float4*)(kp_ + 16 * 3072);                                        \
    kr2 = *(const float4*)(kp_ + 32 * 3072);                                        \
    kr3 = *(const float4*)(kp_ + 48 * 3072);                                        \
    const float* vp_ = qkv + bbase + (size_t)((ks_) + 2 * skey) * 3072 + 2048 + hh * 64 + sdc * 4; \
    va0 = *(const float4*)vp_;               vb0 = *(const float4*)(vp_ +      3072); \
    va1 = *(const float4*)(vp_ + 32 * 3072); vb1 = *(const float4*)(vp_ + 33 * 3072); \
}

#define WK1(m, krm, KB) *(uint2*)((char*)(KB) + ((((skey + 16 * (m)) * 128 + sdc * 8)) ^ ((skey & 7) << 4))) = \
    make_uint2(pk2(krm.x, krm.y), pk2(krm.z, krm.w));
#define WV1(p, vam, vbm, VB) {                                                      \
    const float* A_ = &vam.x; const float* B_ = &vbm.x;                             \
    _Pragma("unroll")                                                               \
    for (int e2 = 0; e2 < 4; ++e2) {                                                \
        int d_ = 4 * sdc + e2;                                                      \
        int off_ = (d_ * 128 + (2 * skey + 32 * (p)) * 2) ^ (((d_ ^ (d_ >> 3)) & 7) << 4); \
        *(unsigned*)((char*)(VB) + off_) = pk2(A_[e2], B_[e2]);                     \
    }                                                                               \
}
#define STAGE_WRITE(nb) {                                                           \
    unsigned short* KB = &Klds[nb][0];                                              \
    WK1(0, kr0, KB) WK1(1, kr1, KB) WK1(2, kr2, KB) WK1(3, kr3, KB)                 \
    unsigned short* VB = &Vtlds[nb][0];                                             \
    WV1(0, va0, vb0, VB) WV1(1, va1, vb1, VB)                                       \
}

    // ---- compute sub-macros (cross-chunk interleaved schedule) ----
#define LDK(kf, kt) {                                                               \
    const int key_ = (kt) * 32 + l31;                                               \
    const int ksw_ = (l31 & 7) << 4;                                                \
    _Pragma("unroll")                                                               \
    for (int ds = 0; ds < 4; ++ds)                                                  \
        kf[ds] = *(const f16x8*)((const char*)(KB) + ((key_ * 128 + ds * 32 + h * 16) ^ ksw_)); \
}
#define LDV(vf, kt) {                                                               \
    _Pragma("unroll")                                                               \
    for (int dt = 0; dt < 2; ++dt) {                                                \
        const int d_ = dt * 32 + l31;                                               \
        const int vsw_ = ((d_ ^ (d_ >> 3)) & 7) << 4;                               \
        _Pragma("unroll")                                                           \
        for (int ksi = 0; ksi < 2; ++ksi)                                           \
            vf[dt][ksi] = *(const f16x8*)((const char*)(VB) + ((d_ * 128 + (kt) * 64 + ksi * 32 + h * 16) ^ vsw_)); \
    }                                                                               \
}
// QK with two partial accumulators: chains of 2, four streams across two chunks
#define QK2(stA, stB, kf) {                                                         \
    stA = (f32x16)(0.f);                                                            \
    stB = (f32x16)(0.f);                                                            \
    stA = MFMA32(kf[0], qf[0], stA);                                                \
    stB = MFMA32(kf[1], qf[1], stB);                                                \
    stA = MFMA32(kf[2], qf[2], stA);                                                \
    stB = MFMA32(kf[3], qf[3], stB);                                                \
}
#define SM(stA, stB, ulo, uhi) {                                                    \
    float psum_ = 0.f;                                                              \
    _Pragma("unroll")                                                               \
    for (int jq = 0; jq < 4; ++jq) {                                                \
        float e0 = __builtin_amdgcn_exp2f(stA[4 * jq + 0] + stB[4 * jq + 0]);       \
        float e1 = __builtin_amdgcn_exp2f(stA[4 * jq + 1] + stB[4 * jq + 1]);       \
        float e2 = __builtin_amdgcn_exp2f(stA[4 * jq + 2] + stB[4 * jq + 2]);       \
        float e3 = __builtin_amdgcn_exp2f(stA[4 * jq + 3] + stB[4 * jq + 3]);       \
        psum_ += (e0 + e1) + (e2 + e3);                                             \
        ulo[jq] = pk2(e0, e1); uhi[jq] = pk2(e2, e3);                               \
    }                                                                               \
    lsum += psum_;                                                                  \
}
// PV onto per-(dt,ksi) accumulators: no intra-chunk or cross-chunk acc chaining
#define PV(ulo, uhi, vf) {                                                          \
    _Pragma("unroll")                                                               \
    for (int ksi = 0; ksi < 2; ++ksi) {                                             \
        i32x2 r0 = __builtin_amdgcn_permlane32_swap((int)ulo[2 * ksi], (int)ulo[2 * ksi + 1], false, false); \
        i32x2 r1 = __builtin_amdgcn_permlane32_swap((int)uhi[2 * ksi], (int)uhi[2 * ksi + 1], false, false); \
        uint4 uw;                                                                   \
        uw.x = (unsigned)r0[0]; uw.y = (unsigned)r1[0];                             \
        uw.z = (unsigned)r0[1]; uw.w = (unsigned)r1[1];                             \
        f16x8 pf = __builtin_bit_cast(f16x8, uw);                                   \
        accs[0][ksi] = MFMA32(vf[0][ksi], pf, accs[0][ksi]);                        \
        accs[1][ksi] = MFMA32(vf[1][ksi], pf, accs[1][ksi]);                        \
    }                                                                               \
}

    // tile t -> key-start (scalar: kbl in SGPR)
#define TB(t_) ((int)(((kbl >> (((t_) >> 2) * 4)) & 15) * 256 + ((t_) & 3) * 64))

    // prologue: tile 0 staged
    STAGE_LOAD(TB(0));
    STAGE_WRITE(0);
    __syncthreads();

    const int ws = w & 1; // wave-parity chunk stagger
    for (int t = 0; t < ntile; ++t) {
        const bool more = (t + 1 < ntile);
        if (more) STAGE_LOAD(TB(t + 1)); // issue early; consumed after compute
        {
            const unsigned short* KB = &Klds[t & 1][0];
            const unsigned short* VB = &Vtlds[t & 1][0];
            const int c0 = 0 ^ ws, c1 = 1 ^ ws;
            f16x8 kf0[4], kf1[4], vf0[2][2], vf1[2][2];
            f32x16 sA0, sB0, sA1, sB1;
            unsigned u0lo[4], u0hi[4], u1lo[4], u1hi[4];
            LDK(kf0, c0);
            LDK(kf1, c1);
            __builtin_amdgcn_s_setprio(1);
            QK2(sA0, sB0, kf0);           // 4 independent MFMA streams
            QK2(sA1, sB1, kf1);           // across the two chunks
            __builtin_amdgcn_s_setprio(0);
            LDV(vf0, c0);
            SM(sA0, sB0, u0lo, u0hi);     // VALU under QK(c1) latency
            LDV(vf1, c1);
            __builtin_amdgcn_s_setprio(1);
            PV(u0lo, u0hi, vf0);          // 4 independent acc streams
            __builtin_amdgcn_s_setprio(0);
            SM(sA1, sB1, u1lo, u1hi);     // VALU under PV(c0) latency
            __builtin_amdgcn_s_setprio(1);
            PV(u1lo, u1hi, vf1);
            __builtin_amdgcn_s_setprio(0);
        }
        if (more) STAGE_WRITE((t + 1) & 1); // other buffer: no read hazard
        __syncthreads();
    }

    // epilogue: sum acc halves, row-sum across lane halves, normalize, store
    lsum += __shfl_xor(lsum, 32);
    const float inv = 1.0f / lsum;
    float* op = out + (((size_t)b * 2048 + (qbase + l31)) * 16 + hh) * 64;
    #pragma unroll
    for (int dt = 0; dt < 2; ++dt)
        #pragma unroll
        for (int jq = 0; jq < 4; ++jq) {
            float4 o;
            o.x = (accs[dt][0][4 * jq + 0] + accs[dt][1][4 * jq + 0]) * inv;
            o.y = (accs[dt][0][4 * jq + 1] + accs[dt][1][4 * jq + 1]) * inv;
            o.z = (accs[dt][0][4 * jq + 2] + accs[dt][1][4 * jq + 2]) * inv;
            o.w = (accs[dt][0][4 * jq + 3] + accs[dt][1][4 * jq + 3]) * inv;
            *(float4*)(op + dt * 32 + 8 * jq + 4 * h) = o;
        }
}

extern "C" void kernel_launch(void* const* d_in, const int* in_sizes, int n_in,
                              void* d_out, int out_size, void* d_ws, size_t ws_size,
                              hipStream_t stream) {
    const float* qkv = (const float*)d_in[0];
    const int* layout = (const int*)d_in[1];
    float* out = (float*)d_out;
    fba_fwd<<<dim3(512), dim3(256), 0, stream>>>(qkv, layout, out);
}

// Round 18
// 24.495 us; speedup vs baseline: 1.0139x; 1.0139x over previous
//
#include <hip/hip_runtime.h>

typedef float f32x4 __attribute__((ext_vector_type(4)));
typedef float f32x16 __attribute__((ext_vector_type(16)));
typedef _Float16 f16x8 __attribute__((ext_vector_type(8)));
typedef __fp16 fp16x2 __attribute__((ext_vector_type(2)));
typedef int i32x2 __attribute__((ext_vector_type(2)));

static __device__ __forceinline__ unsigned pk2(float a, float b) {
    fp16x2 r = __builtin_amdgcn_cvt_pkrtz(a, b); // v_cvt_pkrtz_f16_f32
    return __builtin_bit_cast(unsigned, r);
}
static __device__ __forceinline__ f16x8 pk8(float4 a, float4 b) {
    uint4 u; u.x = pk2(a.x, a.y); u.y = pk2(a.z, a.w);
    u.z = pk2(b.x, b.y); u.w = pk2(b.z, b.w);
    return __builtin_bit_cast(f16x8, u);
}

#define MFMA32(A, B, C) __builtin_amdgcn_mfma_f32_32x32x16_f16((A), (B), (C), 0, 0, 0)

// Barrier with lgkm-only drain: __syncthreads() emits s_waitcnt vmcnt(0) lgkmcnt(0)
// before s_barrier, force-draining the next tile's 8 in-flight global loads (m97-class
// stall). Only lgkmcnt(0) is required here (ds_writes visible before other waves read);
// the global loads feed private regs, ordered by the compiler's counted vmcnt at use.
#define BARRIER_LGKM() { asm volatile("s_waitcnt lgkmcnt(0)" ::: "memory"); \
                         __builtin_amdgcn_s_barrier(); }

// qkv: [2][2048][3][16][64] f32; layout: [128][8] i32; out: [2][2048][16][64] f32
// r15 shell (best 24.26us): wg = 4 waves x 32 q = 128 q-rows (b,h,j,qh), 512 wgs ->
// 2 wg/CU; 64-key K/V tiles dbuf'd in swizzled LDS, 1 barrier/tile; cross-chunk
// interleaved body (QK(c0),QK(c1) back-to-back; SM(c0) under QK(c1); SM(c1) under
// PV(c0)); in-reg P (cvt_pkrtz + permlane32_swap); fixed-base softmax (Q pre-scaled
// by 0.125*log2e); raw v_exp_f32; setprio on MFMA clusters.
// NEW vs r15: BARRIER_LGKM instead of __syncthreads (loads stay in flight across the
// barrier), and the final iteration's barrier is elided (ntile is wg-uniform).
__global__ __launch_bounds__(256, 2) void fba_fwd(const float* __restrict__ qkv,
                                                  const int* __restrict__ layout,
                                                  float* __restrict__ out) {
    __shared__ unsigned short Klds[2][64 * 64];  // [key][d] f16, byte ^= (key&7)<<4
    __shared__ unsigned short Vtlds[2][64 * 64]; // [d][key] f16, byte ^= ((d^(d>>3))&7)<<4

    const int bid = blockIdx.x;
    const int vid = (bid & 7) * 64 + (bid >> 3); // XCD swizzle: one (b,h) per XCD
    const int b = vid >> 8;
    const int hh = (vid >> 4) & 15;
    const int j = (vid >> 1) & 7;
    const int qh = vid & 1;

    const int tid = threadIdx.x;
    const int w = tid >> 6;
    const int lane = tid & 63;
    const int l31 = lane & 31;
    const int h = lane >> 5;

    const size_t bbase = (size_t)b * 2048 * 3072;
    const int qbase = 256 * j + 128 * qh + 32 * w;

    // active K-blocks for this wg's 8 layout rows (uniform): pack ids into nibbles
    unsigned kbl = 0; int nact = 0;
    for (int kb = 0; kb < 8; ++kb) {
        int a = 0;
        #pragma unroll
        for (int r = 0; r < 8; ++r) a |= layout[(16 * j + 8 * qh + r) * 8 + kb];
        if (a) { kbl |= (unsigned)kb << (4 * nact); ++nact; }
    }
    kbl = __builtin_amdgcn_readfirstlane(kbl);
    const int ntile = 4 * nact; // 64-key tiles (wg-uniform)

    // Q frags (B-operand, pre-scaled): lane -> Q[q=qbase+l31][d = ds*16+8h+e] * SC
    const float SC = 0.18033688f; // 0.125 * log2(e)
    f16x8 qf[4];
    {
        const float* qp = qkv + bbase + (size_t)(qbase + l31) * 3072 + hh * 64;
        #pragma unroll
        for (int ds = 0; ds < 4; ++ds) {
            const float* p0 = qp + ds * 16 + 8 * h;
            float4 x = *(const float4*)p0;
            float4 y = *(const float4*)(p0 + 4);
            float4 xs = {x.x * SC, x.y * SC, x.z * SC, x.w * SC};
            float4 ys = {y.x * SC, y.y * SC, y.z * SC, y.w * SC};
            qf[ds] = pk8(xs, ys);
        }
    }

    f32x16 acc[2]; // [dt]: O^T[d = dt*32 + (r&3)+8*(r>>2)+4h][q=l31], unnormalized
    acc[0] = (f32x16)(0.f);
    acc[1] = (f32x16)(0.f);
    float lsum = 0.f;

    // staging thread-constants (256 threads): K keys skey+16m (m<4); V pairs 2skey+32p
    const int skey = tid >> 4;  // 0..15
    const int sdc  = tid & 15;  // d-group of 4 floats

    float4 kr0, kr1, kr2, kr3;  // K prefetch (4 float4)
    float4 va0, vb0, va1, vb1;  // V prefetch (4 float4) -- 8 total: proven no-spill

#define STAGE_LOAD(ks_) {                                                           \
    const float* kp_ = qkv + bbase + (size_t)((ks_) + skey) * 3072 + 1024 + hh * 64 + sdc * 4; \
    kr0 = *(const float4*)kp_;                                                      \
    kr1 = *(const float4*)(kp_ + 16 * 3072);                                        \
    kr2 = *(const float4*)(kp_ + 32 * 3072);                                        \
    kr3 = *(const float4*)(kp_ + 48 * 3072);                                        \
    const float* vp_ = qkv + bbase + (size_t)((ks_) + 2 * skey) * 3072 + 2048 + hh * 64 + sdc * 4; \
    va0 = *(const float4*)vp_;               vb0 = *(const float4*)(vp_ +      3072); \
    va1 = *(const float4*)(vp_ + 32 * 3072); vb1 = *(const float4*)(vp_ + 33 * 3072); \
}

#define WK1(m, krm, KB) *(uint2*)((char*)(KB) + ((((skey + 16 * (m)) * 128 + sdc * 8)) ^ ((skey & 7) << 4))) = \
    make_uint2(pk2(krm.x, krm.y), pk2(krm.z, krm.w));
#define WV1(p, vam, vbm, VB) {                                                      \
    const float* A_ = &vam.x; const float* B_ = &vbm.x;                             \
    _Pragma("unroll")                                                               \
    for (int e2 = 0; e2 < 4; ++e2) {                                                \
        int d_ = 4 * sdc + e2;                                                      \
        int off_ = (d_ * 128 + (2 * skey + 32 * (p)) * 2) ^ (((d_ ^ (d_ >> 3)) & 7) << 4); \
        *(unsigned*)((char*)(VB) + off_) = pk2(A_[e2], B_[e2]);                     \
    }                                                                               \
}
#define STAGE_WRITE(nb) {                                                           \
    unsigned short* KB = &Klds[nb][0];                                              \
    WK1(0, kr0, KB) WK1(1, kr1, KB) WK1(2, kr2, KB) WK1(3, kr3, KB)                 \
    unsigned short* VB = &Vtlds[nb][0];                                             \
    WV1(0, va0, vb0, VB) WV1(1, va1, vb1, VB)                                       \
}

    // ---- compute sub-macros (cross-chunk interleaved schedule) ----
#define LDK(kf, kt) {                                                               \
    const int key_ = (kt) * 32 + l31;                                               \
    const int ksw_ = (l31 & 7) << 4;                                                \
    _Pragma("unroll")                                                               \
    for (int ds = 0; ds < 4; ++ds)                                                  \
        kf[ds] = *(const f16x8*)((const char*)(KB) + ((key_ * 128 + ds * 32 + h * 16) ^ ksw_)); \
}
#define LDV(vf, kt) {                                                               \
    _Pragma("unroll")                                                               \
    for (int dt = 0; dt < 2; ++dt) {                                                \
        const int d_ = dt * 32 + l31;                                               \
        const int vsw_ = ((d_ ^ (d_ >> 3)) & 7) << 4;                               \
        _Pragma("unroll")                                                           \
        for (int ksi = 0; ksi < 2; ++ksi)                                           \
            vf[dt][ksi] = *(const f16x8*)((const char*)(VB) + ((d_ * 128 + (kt) * 64 + ksi * 32 + h * 16) ^ vsw_)); \
    }                                                                               \
}
#define QK(st, kf) {                                                                \
    st = (f32x16)(0.f);                                                             \
    st = MFMA32(kf[0], qf[0], st);                                                  \
    st = MFMA32(kf[1], qf[1], st);                                                  \
    st = MFMA32(kf[2], qf[2], st);                                                  \
    st = MFMA32(kf[3], qf[3], st);                                                  \
}
#define SM(st, ulo, uhi) {                                                          \
    float psum_ = 0.f;                                                              \
    _Pragma("unroll")                                                               \
    for (int jq = 0; jq < 4; ++jq) {                                                \
        float e0 = __builtin_amdgcn_exp2f(st[4 * jq + 0]);                          \
        float e1 = __builtin_amdgcn_exp2f(st[4 * jq + 1]);                          \
        float e2 = __builtin_amdgcn_exp2f(st[4 * jq + 2]);                          \
        float e3 = __builtin_amdgcn_exp2f(st[4 * jq + 3]);                          \
        psum_ += (e0 + e1) + (e2 + e3);                                             \
        ulo[jq] = pk2(e0, e1); uhi[jq] = pk2(e2, e3);                               \
    }                                                                               \
    lsum += psum_;                                                                  \
}
#define PV(ulo, uhi, vf) {                                                          \
    _Pragma("unroll")                                                               \
    for (int ksi = 0; ksi < 2; ++ksi) {                                             \
        i32x2 r0 = __builtin_amdgcn_permlane32_swap((int)ulo[2 * ksi], (int)ulo[2 * ksi + 1], false, false); \
        i32x2 r1 = __builtin_amdgcn_permlane32_swap((int)uhi[2 * ksi], (int)uhi[2 * ksi + 1], false, false); \
        uint4 uw;                                                                   \
        uw.x = (unsigned)r0[0]; uw.y = (unsigned)r1[0];                             \
        uw.z = (unsigned)r0[1]; uw.w = (unsigned)r1[1];                             \
        f16x8 pf = __builtin_bit_cast(f16x8, uw);                                   \
        acc[0] = MFMA32(vf[0][ksi], pf, acc[0]);                                    \
        acc[1] = MFMA32(vf[1][ksi], pf, acc[1]);                                    \
    }                                                                               \
}

    // tile t -> key-start (scalar: kbl in SGPR)
#define TB(t_) ((int)(((kbl >> (((t_) >> 2) * 4)) & 15) * 256 + ((t_) & 3) * 64))

    // prologue: tile 0 staged
    STAGE_LOAD(TB(0));
    STAGE_WRITE(0);
    BARRIER_LGKM();

    const int ws = w & 1; // wave-parity chunk stagger
    for (int t = 0; t < ntile; ++t) {
        const bool more = (t + 1 < ntile);
        if (more) STAGE_LOAD(TB(t + 1)); // in flight across the whole body AND barrier
        {
            const unsigned short* KB = &Klds[t & 1][0];
            const unsigned short* VB = &Vtlds[t & 1][0];
            const int c0 = 0 ^ ws, c1 = 1 ^ ws;
            f16x8 kf0[4], kf1[4], vf0[2][2], vf1[2][2];
            f32x16 st0, st1;
            unsigned u0lo[4], u0hi[4], u1lo[4], u1hi[4];
            LDK(kf0, c0);
            LDK(kf1, c1);
            __builtin_amdgcn_s_setprio(1);
            QK(st0, kf0);                 // chunk-0 QK chain
            QK(st1, kf1);                 // chunk-1 fills chunk-0's latency shadow
            __builtin_amdgcn_s_setprio(0);
            LDV(vf0, c0);
            SM(st0, u0lo, u0hi);          // VALU under QK(c1) MFMA latency
            LDV(vf1, c1);
            __builtin_amdgcn_s_setprio(1);
            PV(u0lo, u0hi, vf0);
            __builtin_amdgcn_s_setprio(0);
            SM(st1, u1lo, u1hi);          // VALU under PV(c0) MFMA latency
            __builtin_amdgcn_s_setprio(1);
            PV(u1lo, u1hi, vf1);
            __builtin_amdgcn_s_setprio(0);
        }
        if (more) {
            STAGE_WRITE((t + 1) & 1);     // counted vmcnt at reg use, not at barrier
            BARRIER_LGKM();               // lgkm-only drain; vmem stays in flight
        }
    }

    // epilogue: row-sum across lane halves, normalize, store
    lsum += __shfl_xor(lsum, 32);
    const float inv = 1.0f / lsum;
    float* op = out + (((size_t)b * 2048 + (qbase + l31)) * 16 + hh) * 64;
    #pragma unroll
    for (int dt = 0; dt < 2; ++dt)
        #pragma unroll
        for (int jq = 0; jq < 4; ++jq) {
            float4 o;
            o.x = acc[dt][4 * jq + 0] * inv;
            o.y = acc[dt][4 * jq + 1] * inv;
            o.z = acc[dt][4 * jq + 2] * inv;
            o.w = acc[dt][4 * jq + 3] * inv;
            *(float4*)(op + dt * 32 + 8 * jq + 4 * h) = o;
        }
}

extern "C" void kernel_launch(void* const* d_in, const int* in_sizes, int n_in,
                              void* d_out, int out_size, void* d_ws, size_t ws_size,
                              hipStream_t stream) {
    const float* qkv = (const float*)d_in[0];
    const int* layout = (const int*)d_in[1];
    float* out = (float*)d_out;
    fba_fwd<<<dim3(512), dim3(256), 0, stream>>>(qkv, layout, out);
}

// Round 19
// 24.246 us; speedup vs baseline: 1.0244x; 1.0103x over previous
//
#include <hip/hip_runtime.h>

typedef float f32x4 __attribute__((ext_vector_type(4)));
typedef float f32x16 __attribute__((ext_vector_type(16)));
typedef _Float16 f16x8 __attribute__((ext_vector_type(8)));
typedef __fp16 fp16x2 __attribute__((ext_vector_type(2)));
typedef int i32x2 __attribute__((ext_vector_type(2)));

static __device__ __forceinline__ unsigned pk2(float a, float b) {
    fp16x2 r = __builtin_amdgcn_cvt_pkrtz(a, b); // v_cvt_pkrtz_f16_f32
    return __builtin_bit_cast(unsigned, r);
}
static __device__ __forceinline__ f16x8 pk8(float4 a, float4 b) {
    uint4 u; u.x = pk2(a.x, a.y); u.y = pk2(a.z, a.w);
    u.z = pk2(b.x, b.y); u.w = pk2(b.z, b.w);
    return __builtin_bit_cast(f16x8, u);
}

#define MFMA32(A, B, C) __builtin_amdgcn_mfma_f32_32x32x16_f16((A), (B), (C), 0, 0, 0)

// qkv: [2][2048][3][16][64] f32; layout: [128][8] i32; out: [2][2048][16][64] f32
// r15 best (24.26us), consolidation round: wg = 4 waves x 32 q = 128 q-rows
// (b,h,j,qh), 512 wgs -> 2 wg/CU; 64-key K/V tiles dbuf'd in swizzled LDS,
// 1 barrier/tile (last elided); cross-chunk interleaved body (QK(c0),QK(c1)
// back-to-back; SM(c0) under QK(c1); SM(c1) under PV(c0)); in-reg P (cvt_pkrtz +
// permlane32_swap); fixed-base softmax (Q pre-scaled by 0.125*log2e); raw v_exp_f32;
// setprio on MFMA clusters. NEW: psum via v_dot2_f32_f16 on the already-packed
// f16x2 P words (16 fdot2 replace ~34 f32 adds/tile; lsum now numerically
// consistent with the f16 P used by PV).
__global__ __launch_bounds__(256, 2) void fba_fwd(const float* __restrict__ qkv,
                                                  const int* __restrict__ layout,
                                                  float* __restrict__ out) {
    __shared__ unsigned short Klds[2][64 * 64];  // [key][d] f16, byte ^= (key&7)<<4
    __shared__ unsigned short Vtlds[2][64 * 64]; // [d][key] f16, byte ^= ((d^(d>>3))&7)<<4

    const int bid = blockIdx.x;
    const int vid = (bid & 7) * 64 + (bid >> 3); // XCD swizzle: one (b,h) per XCD
    const int b = vid >> 8;
    const int hh = (vid >> 4) & 15;
    const int j = (vid >> 1) & 7;
    const int qh = vid & 1;

    const int tid = threadIdx.x;
    const int w = tid >> 6;
    const int lane = tid & 63;
    const int l31 = lane & 31;
    const int h = lane >> 5;

    const size_t bbase = (size_t)b * 2048 * 3072;
    const int qbase = 256 * j + 128 * qh + 32 * w;

    // active K-blocks for this wg's 8 layout rows (uniform): pack ids into nibbles
    unsigned kbl = 0; int nact = 0;
    for (int kb = 0; kb < 8; ++kb) {
        int a = 0;
        #pragma unroll
        for (int r = 0; r < 8; ++r) a |= layout[(16 * j + 8 * qh + r) * 8 + kb];
        if (a) { kbl |= (unsigned)kb << (4 * nact); ++nact; }
    }
    kbl = __builtin_amdgcn_readfirstlane(kbl);
    const int ntile = 4 * nact; // 64-key tiles (wg-uniform)

    // Q frags (B-operand, pre-scaled): lane -> Q[q=qbase+l31][d = ds*16+8h+e] * SC
    const float SC = 0.18033688f; // 0.125 * log2(e)
    f16x8 qf[4];
    {
        const float* qp = qkv + bbase + (size_t)(qbase + l31) * 3072 + hh * 64;
        #pragma unroll
        for (int ds = 0; ds < 4; ++ds) {
            const float* p0 = qp + ds * 16 + 8 * h;
            float4 x = *(const float4*)p0;
            float4 y = *(const float4*)(p0 + 4);
            float4 xs = {x.x * SC, x.y * SC, x.z * SC, x.w * SC};
            float4 ys = {y.x * SC, y.y * SC, y.z * SC, y.w * SC};
            qf[ds] = pk8(xs, ys);
        }
    }

    f32x16 acc[2]; // [dt]: O^T[d = dt*32 + (r&3)+8*(r>>2)+4h][q=l31], unnormalized
    acc[0] = (f32x16)(0.f);
    acc[1] = (f32x16)(0.f);
    float lsum = 0.f;
    const fp16x2 ONE2 = {(__fp16)1.0f, (__fp16)1.0f};

    // staging thread-constants (256 threads): K keys skey+16m (m<4); V pairs 2skey+32p
    const int skey = tid >> 4;  // 0..15
    const int sdc  = tid & 15;  // d-group of 4 floats

    float4 kr0, kr1, kr2, kr3;  // K prefetch (4 float4)
    float4 va0, vb0, va1, vb1;  // V prefetch (4 float4) -- 8 total: proven no-spill

#define STAGE_LOAD(ks_) {                                                           \
    const float* kp_ = qkv + bbase + (size_t)((ks_) + skey) * 3072 + 1024 + hh * 64 + sdc * 4; \
    kr0 = *(const float4*)kp_;                                                      \
    kr1 = *(const float4*)(kp_ + 16 * 3072);                                        \
    kr2 = *(const float4*)(kp_ + 32 * 3072);                                        \
    kr3 = *(const float4*)(kp_ + 48 * 3072);                                        \
    const float* vp_ = qkv + bbase + (size_t)((ks_) + 2 * skey) * 3072 + 2048 + hh * 64 + sdc * 4; \
    va0 = *(const float4*)vp_;               vb0 = *(const float4*)(vp_ +      3072); \
    va1 = *(const float4*)(vp_ + 32 * 3072); vb1 = *(const float4*)(vp_ + 33 * 3072); \
}

#define WK1(m, krm, KB) *(uint2*)((char*)(KB) + ((((skey + 16 * (m)) * 128 + sdc * 8)) ^ ((skey & 7) << 4))) = \
    make_uint2(pk2(krm.x, krm.y), pk2(krm.z, krm.w));
#define WV1(p, vam, vbm, VB) {                                                      \
    const float* A_ = &vam.x; const float* B_ = &vbm.x;                             \
    _Pragma("unroll")                                                               \
    for (int e2 = 0; e2 < 4; ++e2) {                                                \
        int d_ = 4 * sdc + e2;                                                      \
        int off_ = (d_ * 128 + (2 * skey + 32 * (p)) * 2) ^ (((d_ ^ (d_ >> 3)) & 7) << 4); \
        *(unsigned*)((char*)(VB) + off_) = pk2(A_[e2], B_[e2]);                     \
    }                                                                               \
}
#define STAGE_WRITE(nb) {                                                           \
    unsigned short* KB = &Klds[nb][0];                                              \
    WK1(0, kr0, KB) WK1(1, kr1, KB) WK1(2, kr2, KB) WK1(3, kr3, KB)                 \
    unsigned short* VB = &Vtlds[nb][0];                                             \
    WV1(0, va0, vb0, VB) WV1(1, va1, vb1, VB)                                       \
}

    // ---- compute sub-macros (cross-chunk interleaved schedule) ----
#define LDK(kf, kt) {                                                               \
    const int key_ = (kt) * 32 + l31;                                               \
    const int ksw_ = (l31 & 7) << 4;                                                \
    _Pragma("unroll")                                                               \
    for (int ds = 0; ds < 4; ++ds)                                                  \
        kf[ds] = *(const f16x8*)((const char*)(KB) + ((key_ * 128 + ds * 32 + h * 16) ^ ksw_)); \
}
#define LDV(vf, kt) {                                                               \
    _Pragma("unroll")                                                               \
    for (int dt = 0; dt < 2; ++dt) {                                                \
        const int d_ = dt * 32 + l31;                                               \
        const int vsw_ = ((d_ ^ (d_ >> 3)) & 7) << 4;                               \
        _Pragma("unroll")                                                           \
        for (int ksi = 0; ksi < 2; ++ksi)                                           \
            vf[dt][ksi] = *(const f16x8*)((const char*)(VB) + ((d_ * 128 + (kt) * 64 + ksi * 32 + h * 16) ^ vsw_)); \
    }                                                                               \
}
#define QK(st, kf) {                                                                \
    st = (f32x16)(0.f);                                                             \
    st = MFMA32(kf[0], qf[0], st);                                                  \
    st = MFMA32(kf[1], qf[1], st);                                                  \
    st = MFMA32(kf[2], qf[2], st);                                                  \
    st = MFMA32(kf[3], qf[3], st);                                                  \
}
#define SM(st, ulo, uhi) {                                                          \
    _Pragma("unroll")                                                               \
    for (int jq = 0; jq < 4; ++jq) {                                                \
        float e0 = __builtin_amdgcn_exp2f(st[4 * jq + 0]);                          \
        float e1 = __builtin_amdgcn_exp2f(st[4 * jq + 1]);                          \
        float e2 = __builtin_amdgcn_exp2f(st[4 * jq + 2]);                          \
        float e3 = __builtin_amdgcn_exp2f(st[4 * jq + 3]);                          \
        ulo[jq] = pk2(e0, e1); uhi[jq] = pk2(e2, e3);                               \
        lsum = __builtin_amdgcn_fdot2(__builtin_bit_cast(fp16x2, ulo[jq]), ONE2, lsum, false); \
        lsum = __builtin_amdgcn_fdot2(__builtin_bit_cast(fp16x2, uhi[jq]), ONE2, lsum, false); \
    }                                                                               \
}
#define PV(ulo, uhi, vf) {                                                          \
    _Pragma("unroll")                                                               \
    for (int ksi = 0; ksi < 2; ++ksi) {                                             \
        i32x2 r0 = __builtin_amdgcn_permlane32_swap((int)ulo[2 * ksi], (int)ulo[2 * ksi + 1], false, false); \
        i32x2 r1 = __builtin_amdgcn_permlane32_swap((int)uhi[2 * ksi], (int)uhi[2 * ksi + 1], false, false); \
        uint4 uw;                                                                   \
        uw.x = (unsigned)r0[0]; uw.y = (unsigned)r1[0];                             \
        uw.z = (unsigned)r0[1]; uw.w = (unsigned)r1[1];                             \
        f16x8 pf = __builtin_bit_cast(f16x8, uw);                                   \
        acc[0] = MFMA32(vf[0][ksi], pf, acc[0]);                                    \
        acc[1] = MFMA32(vf[1][ksi], pf, acc[1]);                                    \
    }                                                                               \
}

    // tile t -> key-start (scalar: kbl in SGPR)
#define TB(t_) ((int)(((kbl >> (((t_) >> 2) * 4)) & 15) * 256 + ((t_) & 3) * 64))

    // prologue: tile 0 staged
    STAGE_LOAD(TB(0));
    STAGE_WRITE(0);
    __syncthreads();

    const int ws = w & 1; // wave-parity chunk stagger
    for (int t = 0; t < ntile; ++t) {
        const bool more = (t + 1 < ntile);
        if (more) STAGE_LOAD(TB(t + 1)); // issue early; consumed after compute
        {
            const unsigned short* KB = &Klds[t & 1][0];
            const unsigned short* VB = &Vtlds[t & 1][0];
            const int c0 = 0 ^ ws, c1 = 1 ^ ws;
            f16x8 kf0[4], kf1[4], vf0[2][2], vf1[2][2];
            f32x16 st0, st1;
            unsigned u0lo[4], u0hi[4], u1lo[4], u1hi[4];
            LDK(kf0, c0);
            LDK(kf1, c1);
            __builtin_amdgcn_s_setprio(1);
            QK(st0, kf0);                 // chunk-0 QK chain
            QK(st1, kf1);                 // chunk-1 fills chunk-0's latency shadow
            __builtin_amdgcn_s_setprio(0);
            LDV(vf0, c0);
            SM(st0, u0lo, u0hi);          // VALU under QK(c1) MFMA latency
            LDV(vf1, c1);
            __builtin_amdgcn_s_setprio(1);
            PV(u0lo, u0hi, vf0);
            __builtin_amdgcn_s_setprio(0);
            SM(st1, u1lo, u1hi);          // VALU under PV(c0) MFMA latency
            __builtin_amdgcn_s_setprio(1);
            PV(u1lo, u1hi, vf1);
            __builtin_amdgcn_s_setprio(0);
        }
        if (more) {
            STAGE_WRITE((t + 1) & 1);     // other buffer: no read hazard
            __syncthreads();              // one barrier per tile; last elided
        }
    }

    // epilogue: row-sum across lane halves, normalize, store
    lsum += __shfl_xor(lsum, 32);
    const float inv = 1.0f / lsum;
    float* op = out + (((size_t)b * 2048 + (qbase + l31)) * 16 + hh) * 64;
    #pragma unroll
    for (int dt = 0; dt < 2; ++dt)
        #pragma unroll
        for (int jq = 0; jq < 4; ++jq) {
            float4 o;
            o.x = acc[dt][4 * jq + 0] * inv;
            o.y = acc[dt][4 * jq + 1] * inv;
            o.z = acc[dt][4 * jq + 2] * inv;
            o.w = acc[dt][4 * jq + 3] * inv;
            *(float4*)(op + dt * 32 + 8 * jq + 4 * h) = o;
        }
}

extern "C" void kernel_launch(void* const* d_in, const int* in_sizes, int n_in,
                              void* d_out, int out_size, void* d_ws, size_t ws_size,
                              hipStream_t stream) {
    const float* qkv = (const float*)d_in[0];
    const int* layout = (const int*)d_in[1];
    float* out = (float*)d_out;
    fba_fwd<<<dim3(512), dim3(256), 0, stream>>>(qkv, layout, out);
}